// Round 12
// baseline (162.867 us; speedup 1.0000x reference)
//
#include <hip/hip_runtime.h>
#include <stdint.h>

typedef float    f32x4 __attribute__((ext_vector_type(4)));
typedef short    s16x8 __attribute__((ext_vector_type(8)));
typedef short    s16x4 __attribute__((ext_vector_type(4)));
typedef unsigned short u16;
typedef uint32_t u32;

#define DEVINL __device__ __forceinline__

DEVINL float bf2f(u16 u) { union { u32 i; float f; } x; x.i = ((u32)u) << 16; return x.f; }
DEVINL u16 f2bf(float f) {
  union { float f; u32 i; } x; x.f = f;
  u32 i = x.i;
  return (u16)((i + 0x7FFFu + ((i >> 16) & 1u)) >> 16);  // RNE
}

DEVINL void gload16(const void* g, void* l) {
  __builtin_amdgcn_global_load_lds((const __attribute__((address_space(1))) void*)g,
                                   (__attribute__((address_space(3))) void*)l,
                                   16, 0, 0);
}

// --------------------------- prep: conv x->bf16 + both weight transposes
__global__ __launch_bounds__(256) void k_prep(const float* __restrict__ x,
                                              u16* __restrict__ xb,
                                              const float* __restrict__ Wqkv,
                                              u16* __restrict__ wqkvt,
                                              const float* __restrict__ Wout,
                                              u16* __restrict__ woutt) {
  __shared__ __align__(16) float t[64][65];
  int b = blockIdx.x;
  int tid = threadIdx.x;
  if (b < 2048) {
    const int n8 = 2097152;
    int stride = 2048 * 256;
    for (int i = b * 256 + tid; i < n8; i += stride) {
      const f32x4* p = (const f32x4*)(x + (size_t)i * 8);
      f32x4 a = p[0], c = p[1];
      s16x8 o;
      o[0] = (short)f2bf(a[0]); o[1] = (short)f2bf(a[1]);
      o[2] = (short)f2bf(a[2]); o[3] = (short)f2bf(a[3]);
      o[4] = (short)f2bf(c[0]); o[5] = (short)f2bf(c[1]);
      o[6] = (short)f2bf(c[2]); o[7] = (short)f2bf(c[3]);
      *(s16x8*)(xb + (size_t)i * 8) = o;
    }
    return;
  }
  const float* W; u16* Wt; int K, N, tb;
  if (b < 2048 + 192) { W = Wqkv; Wt = wqkvt; K = 512; N = 1536; tb = b - 2048; }
  else               { W = Wout; Wt = woutt; K = 512; N = 512;  tb = b - 2240; }
  int nb = N >> 6;
  int tn = tb % nb, tk = tb / nb;
  int n0 = tn << 6, k0 = tk << 6;
  int cr = tid >> 4, cc = (tid & 15) << 2;
#pragma unroll
  for (int i = 0; i < 4; i++) {
    int r = cr + (i << 4);
    f32x4 v = *(const f32x4*)(W + (size_t)(k0 + r) * N + n0 + cc);
    t[r][cc] = v[0]; t[r][cc + 1] = v[1]; t[r][cc + 2] = v[2]; t[r][cc + 3] = v[3];
  }
  __syncthreads();
#pragma unroll
  for (int i = 0; i < 4; i++) {
    int nn = cr + (i << 4);
    s16x4 o;
    o[0] = (short)f2bf(t[cc    ][nn]);
    o[1] = (short)f2bf(t[cc + 1][nn]);
    o[2] = (short)f2bf(t[cc + 2][nn]);
    o[3] = (short)f2bf(t[cc + 3][nn]);
    *(s16x4*)(Wt + (size_t)(n0 + nn) * K + k0 + cc) = o;
  }
}

// ------------------------------------------------------------------ GEMM1
// OCCUPANCY EXPERIMENT: 128x128 tile, 256 thr (2x2 waves, wave tile 64x64),
// BK=32, 2-buf LDS = 32 KB, __launch_bounds__(256,4) -> 4 blocks / 16 waves
// per CU (2x all prior rounds; m114's multi-block overlap mechanism).
// r3 ledger: stage(t+1) at tile top into ~par (freed by prev barrier),
// per-tile vmcnt(0)+barrier (drain hidden by co-resident blocks).
// Epilogue: q direct (+phi); k/v transposed s16x4 stores (r9-verified).
__global__ __launch_bounds__(256, 4) void k_g1(
    const u16* __restrict__ A, const u16* __restrict__ Bt,
    u16* __restrict__ qph, u16* __restrict__ kphT, u16* __restrict__ vT) {
  __shared__ __align__(16) u16 lsA[2][128 * 32];
  __shared__ __align__(16) u16 lsB[2][128 * 32];
  const int nbn = 12;
  int nwg = gridDim.x, bx = blockIdx.x;
  int o = (bx & 7) * (nwg >> 3) + (bx >> 3);   // XCD swizzle (3072%8==0)
  int bm = o / nbn, bn = o % nbn;              // M-major: consecutive o share A
  int m0 = bm << 7, n0 = bn << 7;
  int tid = threadIdx.x, w = tid >> 6, lane = tid & 63;
  int lnlo = lane & 15, lnhi = lane >> 4;
  int wr = w >> 1, wc = w & 1;

  // staging: A,B each 128 rows x 4 chunks(16B) = 512 chunks; thread owns
  // c = tid, tid+256. LDS linear; global chunk pre-swizzled ch^((row>>1)&3).
  const u16* gAp[2]; const u16* gBp[2]; int ldst[2];
#pragma unroll
  for (int i = 0; i < 2; i++) {
    int c = tid + i * 256, row = c >> 2, ch = c & 3;
    int gch = ch ^ ((row >> 1) & 3);
    gAp[i] = A + (size_t)(m0 + row) * 512 + gch * 8;
    gBp[i] = Bt + (size_t)(n0 + row) * 512 + gch * 8;
    ldst[i] = c * 8;
  }
  int offA[4], offB[4];
#pragma unroll
  for (int f = 0; f < 4; f++) {
    int rA = wr * 64 + f * 16 + lnlo;
    offA[f] = rA * 32 + (lnhi ^ ((rA >> 1) & 3)) * 8;
    int rB = wc * 64 + f * 16 + lnlo;
    offB[f] = rB * 32 + (lnhi ^ ((rB >> 1) & 3)) * 8;
  }

  f32x4 acc[4][4] = {};

#pragma unroll
  for (int i = 0; i < 2; i++) gload16(gAp[i], &lsA[0][ldst[i]]);
#pragma unroll
  for (int i = 0; i < 2; i++) gload16(gBp[i], &lsB[0][ldst[i]]);
  asm volatile("s_waitcnt vmcnt(0)" ::: "memory");
  __builtin_amdgcn_s_barrier();

#pragma unroll
  for (int t = 0; t < 16; t++) {
    int par = t & 1;
    if (t < 15) {
      int k1 = (t + 1) * 32;
#pragma unroll
      for (int i = 0; i < 2; i++) gload16(gAp[i] + k1, &lsA[par ^ 1][ldst[i]]);
#pragma unroll
      for (int i = 0; i < 2; i++) gload16(gBp[i] + k1, &lsB[par ^ 1][ldst[i]]);
    }
    s16x8 af[4], bf[4];
#pragma unroll
    for (int f = 0; f < 4; f++) af[f] = *(const s16x8*)&lsA[par][offA[f]];
#pragma unroll
    for (int f = 0; f < 4; f++) bf[f] = *(const s16x8*)&lsB[par][offB[f]];
    __builtin_amdgcn_s_setprio(1);
#pragma unroll
    for (int mf = 0; mf < 4; mf++)
#pragma unroll
      for (int nf = 0; nf < 4; nf++)
        acc[mf][nf] = __builtin_amdgcn_mfma_f32_16x16x32_bf16(af[mf], bf[nf], acc[mf][nf], 0, 0, 0);
    __builtin_amdgcn_s_setprio(0);
    if (t < 15) {
      asm volatile("s_waitcnt vmcnt(0)" ::: "memory");
      __builtin_amdgcn_s_barrier();
    }
  }

  int gmB = m0 + wr * 64;
  int gnB = n0 + wc * 64;
  int sec = n0 >> 9;                 // block-uniform (128-col tile in 512 sect)
  if (sec == 0) {
#pragma unroll
    for (int mf = 0; mf < 4; mf++) {
#pragma unroll
      for (int nf = 0; nf < 4; nf++) {
        int col = gnB + nf * 16 + lnlo;
        int hh = (col >> 6) & 7;
        int dd = col & 63;
#pragma unroll
        for (int r = 0; r < 4; r++) {
          int rowm = gmB + mf * 16 + lnhi * 4 + r;
          float val = acc[mf][nf][r];
          val = (val > 0.f) ? (val + 1.f) : __expf(val);  // elu+1
          int bidx = rowm >> 12, tok = rowm & 4095;
          qph[(((size_t)(bidx * 8 + hh) * 4096 + tok) << 6) + dd] = f2bf(val);
        }
      }
    }
  } else {
    u16* dstT = (sec == 1) ? kphT : vT;    // [bh][d=64][n=4096]
    bool isphi = (sec == 1);
#pragma unroll
    for (int mf = 0; mf < 4; mf++) {
      int rowm = gmB + mf * 16 + lnhi * 4;
      int bidx = rowm >> 12, tok = rowm & 4095;
#pragma unroll
      for (int nf = 0; nf < 4; nf++) {
        int col = gnB + nf * 16 + lnlo;
        int hh = (col >> 6) & 7;
        int dd = col & 63;
        s16x4 o4;
#pragma unroll
        for (int r = 0; r < 4; r++) {
          float val = acc[mf][nf][r];
          if (isphi) val = (val > 0.f) ? (val + 1.f) : __expf(val);
          o4[r] = (short)f2bf(val);
        }
        *(s16x4*)&dstT[((size_t)(bidx * 8 + hh) * 64 + dd) * 4096 + tok] = o4;
      }
    }
  }
}

// -------------------------------------------- KV partials via MFMA + Ksum
__global__ __launch_bounds__(256, 2) void k_kv(const u16* __restrict__ kphT,
                                               const u16* __restrict__ vT,
                                               float* __restrict__ kvpart,
                                               float* __restrict__ kspart) {
  __shared__ __align__(16) u16 lsK[64 * 256];
  __shared__ __align__(16) u16 lsV[64 * 256];
  __shared__ float red[4][64];
  int bx = blockIdx.x;
  int bh = bx >> 4, ck = bx & 15;
  int tid = threadIdx.x, w = tid >> 6, lane = tid & 63;
  int lnlo = lane & 15, lnhi = lane >> 4;
  size_t gbase = (size_t)bh * 64 * 4096 + ck * 256;

#pragma unroll
  for (int i = 0; i < 8; i++) {
    int c = tid + i * 256;
    int row = c >> 5, ch = c & 31;
    int gch = ch ^ (row & 31);
    gload16(kphT + gbase + (size_t)row * 4096 + gch * 8, &lsK[c * 8]);
  }
#pragma unroll
  for (int i = 0; i < 8; i++) {
    int c = tid + i * 256;
    int row = c >> 5, ch = c & 31;
    int gch = ch ^ (row & 31);
    gload16(vT + gbase + (size_t)row * 4096 + gch * 8, &lsV[c * 8]);
  }
  asm volatile("s_waitcnt vmcnt(0)" ::: "memory");
  __builtin_amdgcn_s_barrier();

  f32x4 acc[4] = {{0.f, 0.f, 0.f, 0.f}, {0.f, 0.f, 0.f, 0.f},
                  {0.f, 0.f, 0.f, 0.f}, {0.f, 0.f, 0.f, 0.f}};
  int rb = w * 16 + lnlo;
#pragma unroll
  for (int kk = 0; kk < 8; kk++) {
    s16x8 bfr = *(const s16x8*)&lsV[rb * 256 + ((kk * 4 + lnhi) ^ (rb & 31)) * 8];
#pragma unroll
    for (int mf = 0; mf < 4; mf++) {
      int ra = mf * 16 + lnlo;
      s16x8 af = *(const s16x8*)&lsK[ra * 256 + ((kk * 4 + lnhi) ^ (ra & 31)) * 8];
      acc[mf] = __builtin_amdgcn_mfma_f32_16x16x32_bf16(af, bfr, acc[mf], 0, 0, 0);
    }
  }

  {
    int d = tid & 63, q = tid >> 6;
    float s = 0.f;
#pragma unroll
    for (int j = 0; j < 8; j++) {
      s16x8 v8 = *(const s16x8*)&lsK[d * 256 + (q * 8 + j) * 8];
#pragma unroll
      for (int e = 0; e < 8; e++) s += bf2f((u16)v8[e]);
    }
    red[q][d] = s;
  }
  __syncthreads();

  size_t pb = (size_t)(bh * 16 + ck) * 4096;
#pragma unroll
  for (int mf = 0; mf < 4; mf++)
#pragma unroll
    for (int r = 0; r < 4; r++)
      kvpart[pb + (size_t)(mf * 16 + lnhi * 4 + r) * 64 + (w * 16 + lnlo)] = acc[mf][r];
  if (tid < 64)
    kspart[(size_t)(bh * 16 + ck) * 64 + tid] =
        red[0][tid] + red[1][tid] + red[2][tid] + red[3][tid];
}

// ---------------------------------------------- W2 + scaled qphi
// blocks [0,64): bh -> W2T[b][n][h*64+d] = (reduce kvpart) @ woutt
// blocks [64,576): (bh, tok-chunk) -> qphs[bh][tok][d] = qphi*rdn (bf16)
__global__ __launch_bounds__(256) void k_w2(const float* __restrict__ kvpart,
                                            const float* __restrict__ kspart,
                                            const u16* __restrict__ woutt,
                                            const u16* __restrict__ qphi,
                                            u16* __restrict__ w2t,
                                            u16* __restrict__ qphs) {
  __shared__ __align__(16) u16 kvls[64 * 64];
  __shared__ float ksumv[64];
  int blk = blockIdx.x, tid = threadIdx.x;
  if (blk < 64) {
    int bh = blk, b = bh >> 3, h = bh & 7;
    int w = tid >> 6, lane = tid & 63, lnlo = lane & 15, lnhi = lane >> 4;
    int d = tid >> 2, e0 = (tid & 3) << 4;
    size_t pb = (size_t)bh * 16 * 4096;
    f32x4 s0 = {}, s1 = {}, s2 = {}, s3 = {};
    for (int c = 0; c < 16; c++) {
      const float* p = kvpart + pb + (size_t)c * 4096 + d * 64 + e0;
      s0 += *(const f32x4*)(p);
      s1 += *(const f32x4*)(p + 4);
      s2 += *(const f32x4*)(p + 8);
      s3 += *(const f32x4*)(p + 12);
    }
    s16x8 o0, o1;
#pragma unroll
    for (int j = 0; j < 4; j++) {
      o0[j] = (short)f2bf(s0[j]); o0[4 + j] = (short)f2bf(s1[j]);
      o1[j] = (short)f2bf(s2[j]); o1[4 + j] = (short)f2bf(s3[j]);
    }
    int ch0 = e0 >> 3;
    *(s16x8*)&kvls[d * 64 + (ch0 ^ (d & 7)) * 8] = o0;
    *(s16x8*)&kvls[d * 64 + ((ch0 + 1) ^ (d & 7)) * 8] = o1;
    __syncthreads();
    f32x4 acc[4][8] = {};
#pragma unroll
    for (int kk = 0; kk < 2; kk++) {
      s16x8 af[4], bfr[8];
#pragma unroll
      for (int mf = 0; mf < 4; mf++) {
        int r = mf * 16 + lnlo;
        af[mf] = *(const s16x8*)&kvls[r * 64 + ((kk * 4 + lnhi) ^ (r & 7)) * 8];
      }
#pragma unroll
      for (int nf = 0; nf < 8; nf++) {
        int n = w * 128 + nf * 16 + lnlo;
        bfr[nf] = *(const s16x8*)&woutt[(size_t)n * 512 + h * 64 + (kk * 4 + lnhi) * 8];
      }
#pragma unroll
      for (int mf = 0; mf < 4; mf++)
#pragma unroll
        for (int nf = 0; nf < 8; nf++)
          acc[mf][nf] = __builtin_amdgcn_mfma_f32_16x16x32_bf16(af[mf], bfr[nf], acc[mf][nf], 0, 0, 0);
    }
#pragma unroll
    for (int mf = 0; mf < 4; mf++)
#pragma unroll
      for (int nf = 0; nf < 8; nf++) {
        int n = w * 128 + nf * 16 + lnlo;
        s16x4 o4;
#pragma unroll
        for (int r = 0; r < 4; r++) o4[r] = (short)f2bf(acc[mf][nf][r]);
        *(s16x4*)&w2t[(size_t)b * 262144 + (size_t)n * 512 + h * 64 + mf * 16 + lnhi * 4] = o4;
      }
  } else {
    int blk2 = blk - 64;
    int bh = blk2 >> 3, tch = blk2 & 7;
    if (tid < 64) {
      float s = 0.f;
#pragma unroll
      for (int c = 0; c < 16; c++) s += kspart[(size_t)bh * 1024 + c * 64 + tid];
      ksumv[tid] = s;
    }
    __syncthreads();
#pragma unroll
    for (int tt = 0; tt < 2; tt++) {
      int tok = tch * 512 + tt * 256 + tid;
      const u16* qp = qphi + ((size_t)bh * 4096 + tok) * 64;
      s16x8 v8[8];
      float den = 0.f;
#pragma unroll
      for (int cch = 0; cch < 8; cch++) {
        v8[cch] = *(const s16x8*)(qp + cch * 8);
#pragma unroll
        for (int j = 0; j < 8; j++) den += bf2f((u16)v8[cch][j]) * ksumv[cch * 8 + j];
      }
      float rdn = 1.f / (den + 1e-6f);
      u16* qd = qphs + ((size_t)bh * 4096 + tok) * 64;
#pragma unroll
      for (int cch = 0; cch < 8; cch++) {
        s16x8 oo;
#pragma unroll
        for (int j = 0; j < 8; j++) oo[j] = (short)f2bf(bf2f((u16)v8[cch][j]) * rdn);
        *(s16x8*)(qd + cch * 8) = oo;
      }
    }
  }
}

// ----------------------------------------------------------------- k_out
// out[m][n] = qphs_gather[m][k] @ W2T[b][n][k] + bias[n]. Same 128x128
// occupancy-4 structure as k_g1; A gathered across h-planes of qphs.
__global__ __launch_bounds__(256, 4) void k_out(
    const u16* __restrict__ qphs, const u16* __restrict__ w2t,
    const float* __restrict__ bias, float* __restrict__ out) {
  __shared__ __align__(16) u16 lsA[2][128 * 32];
  __shared__ __align__(16) u16 lsB[2][128 * 32];
  const int nbn = 4;
  int nwg = gridDim.x, bx = blockIdx.x;
  int o = (bx & 7) * (nwg >> 3) + (bx >> 3);   // 1024%8==0
  int bm = o / nbn, bn = o % nbn;
  int m0 = bm << 7, n0 = bn << 7;
  int b = m0 >> 12;
  int tid = threadIdx.x, w = tid >> 6, lane = tid & 63;
  int lnlo = lane & 15, lnhi = lane >> 4;
  int wr = w >> 1, wc = w & 1;

  const u16* qb_[2]; const u16* gBp[2]; int ldst[2];
#pragma unroll
  for (int i = 0; i < 2; i++) {
    int c = tid + i * 256, row = c >> 2, ch = c & 3;
    int gch = ch ^ ((row >> 1) & 3);
    int tok = (m0 + row) & 4095;
    qb_[i] = qphs + ((size_t)(b * 8) * 4096 + tok) * 64 + gch * 8;
    gBp[i] = w2t + (size_t)b * 262144 + (size_t)(n0 + row) * 512 + gch * 8;
    ldst[i] = c * 8;
  }
  int offA[4], offB[4];
#pragma unroll
  for (int f = 0; f < 4; f++) {
    int rA = wr * 64 + f * 16 + lnlo;
    offA[f] = rA * 32 + (lnhi ^ ((rA >> 1) & 3)) * 8;
    int rB = wc * 64 + f * 16 + lnlo;
    offB[f] = rB * 32 + (lnhi ^ ((rB >> 1) & 3)) * 8;
  }

  f32x4 acc[4][4] = {};

  auto stageA = [&](int t, int buf) {
    size_t hoff = (size_t)(t >> 1) * 262144 + (t & 1) * 32;
#pragma unroll
    for (int i = 0; i < 2; i++) gload16(qb_[i] + hoff, &lsA[buf][ldst[i]]);
  };
#pragma unroll
  for (int i = 0; i < 2; i++) gload16(gBp[i], &lsB[0][ldst[i]]);
  stageA(0, 0);
  asm volatile("s_waitcnt vmcnt(0)" ::: "memory");
  __builtin_amdgcn_s_barrier();

#pragma unroll
  for (int t = 0; t < 16; t++) {
    int par = t & 1;
    if (t < 15) {
      int k1 = (t + 1) * 32;
      stageA(t + 1, par ^ 1);
#pragma unroll
      for (int i = 0; i < 2; i++) gload16(gBp[i] + k1, &lsB[par ^ 1][ldst[i]]);
    }
    s16x8 af[4], bf[4];
#pragma unroll
    for (int f = 0; f < 4; f++) af[f] = *(const s16x8*)&lsA[par][offA[f]];
#pragma unroll
    for (int f = 0; f < 4; f++) bf[f] = *(const s16x8*)&lsB[par][offB[f]];
    __builtin_amdgcn_s_setprio(1);
#pragma unroll
    for (int mf = 0; mf < 4; mf++)
#pragma unroll
      for (int nf = 0; nf < 4; nf++)
        acc[mf][nf] = __builtin_amdgcn_mfma_f32_16x16x32_bf16(af[mf], bf[nf], acc[mf][nf], 0, 0, 0);
    __builtin_amdgcn_s_setprio(0);
    if (t < 15) {
      asm volatile("s_waitcnt vmcnt(0)" ::: "memory");
      __builtin_amdgcn_s_barrier();
    }
  }

  int gmB = m0 + wr * 64;
  int gnB = n0 + wc * 64;
#pragma unroll
  for (int mf = 0; mf < 4; mf++) {
#pragma unroll
    for (int nf = 0; nf < 4; nf++) {
      int col = gnB + nf * 16 + lnlo;
      float bv = bias[col];
#pragma unroll
      for (int r = 0; r < 4; r++) {
        int rowm = gmB + mf * 16 + lnhi * 4 + r;
        out[(size_t)rowm * 512 + col] = acc[mf][nf][r] + bv;
      }
    }
  }
}

// ------------------------------------------------------------------ launch
#define OFF_XB     ((size_t)0)             // 33.5MB xb; after GEMM1: w2t
#define OFF_W2T    ((size_t)0)             //  4,194,304 (alias xb)
#define OFF_WQKVT  ((size_t)33554432)      //  1,572,864
#define OFF_WOUTT  ((size_t)35127296)      //    524,288
#define OFF_QPHI   ((size_t)35651584)      // 33,554,432
#define OFF_KPHI   ((size_t)69206016)      // 33,554,432 (kphiT; later qphs)
#define OFF_VBUF   ((size_t)102760448)     // 33,554,432 (vT [bh][64][4096])
#define OFF_KVPART ((size_t)136314880)     // 16,777,216
#define OFF_KSPART ((size_t)153092096)     //    262,144

extern "C" void kernel_launch(void* const* d_in, const int* in_sizes, int n_in,
                              void* d_out, int out_size, void* d_ws, size_t ws_size,
                              hipStream_t stream) {
  const float* x    = (const float*)d_in[0];
  const float* Wqkv = (const float*)d_in[1];
  const float* Wout = (const float*)d_in[2];
  const float* bout = (const float*)d_in[3];
  float* out = (float*)d_out;
  char* ws = (char*)d_ws;

  u16* xb     = (u16*)(ws + OFF_XB);
  u16* w2t    = (u16*)(ws + OFF_W2T);    // alias: xb dead after GEMM1
  u16* wqkvt  = (u16*)(ws + OFF_WQKVT);
  u16* woutt  = (u16*)(ws + OFF_WOUTT);
  u16* qphi   = (u16*)(ws + OFF_QPHI);
  u16* kphT   = (u16*)(ws + OFF_KPHI);
  u16* qphs   = (u16*)(ws + OFF_KPHI);   // alias: kphT dead after k_kv
  u16* vT     = (u16*)(ws + OFF_VBUF);
  float* kvpart = (float*)(ws + OFF_KVPART);
  float* kspart = (float*)(ws + OFF_KSPART);

  k_prep<<<2304, 256, 0, stream>>>(x, xb, Wqkv, wqkvt, Wout, woutt);
  // qkv = xb @ Wqkv. 256 Mtiles x 12 Ntiles = 3072 blocks, 4/CU.
  k_g1<<<3072, 256, 0, stream>>>(xb, wqkvt, qphi, kphT, vT);
  k_kv<<<1024, 256, 0, stream>>>(kphT, vT, kvpart, kspart);
  k_w2<<<576, 256, 0, stream>>>(kvpart, kspart, woutt, qphi, w2t, qphs);
  // out = qphs @ W2T + b. 256 Mtiles x 4 Ntiles = 1024 blocks, 4/CU.
  k_out<<<1024, 256, 0, stream>>>(qphs, w2t, bout, out);
}

// Round 13
// 157.524 us; speedup vs baseline: 1.0339x; 1.0339x over previous
//
#include <hip/hip_runtime.h>
#include <stdint.h>

typedef float    f32x4 __attribute__((ext_vector_type(4)));
typedef short    s16x8 __attribute__((ext_vector_type(8)));
typedef short    s16x4 __attribute__((ext_vector_type(4)));
typedef unsigned short u16;
typedef uint32_t u32;

#define DEVINL __device__ __forceinline__

DEVINL float bf2f(u16 u) { union { u32 i; float f; } x; x.i = ((u32)u) << 16; return x.f; }
DEVINL u16 f2bf(float f) {
  union { float f; u32 i; } x; x.f = f;
  u32 i = x.i;
  return (u16)((i + 0x7FFFu + ((i >> 16) & 1u)) >> 16);  // RNE
}

DEVINL void gload16(const void* g, void* l) {
  __builtin_amdgcn_global_load_lds((const __attribute__((address_space(1))) void*)g,
                                   (__attribute__((address_space(3))) void*)l,
                                   16, 0, 0);
}

// --------------------------- prep: conv x->bf16 + both weight transposes
__global__ __launch_bounds__(256) void k_prep(const float* __restrict__ x,
                                              u16* __restrict__ xb,
                                              const float* __restrict__ Wqkv,
                                              u16* __restrict__ wqkvt,
                                              const float* __restrict__ Wout,
                                              u16* __restrict__ woutt) {
  __shared__ __align__(16) float t[64][65];
  int b = blockIdx.x;
  int tid = threadIdx.x;
  if (b < 2048) {
    const int n8 = 2097152;
    int stride = 2048 * 256;
    for (int i = b * 256 + tid; i < n8; i += stride) {
      const f32x4* p = (const f32x4*)(x + (size_t)i * 8);
      f32x4 a = p[0], c = p[1];
      s16x8 o;
      o[0] = (short)f2bf(a[0]); o[1] = (short)f2bf(a[1]);
      o[2] = (short)f2bf(a[2]); o[3] = (short)f2bf(a[3]);
      o[4] = (short)f2bf(c[0]); o[5] = (short)f2bf(c[1]);
      o[6] = (short)f2bf(c[2]); o[7] = (short)f2bf(c[3]);
      *(s16x8*)(xb + (size_t)i * 8) = o;
    }
    return;
  }
  const float* W; u16* Wt; int K, N, tb;
  if (b < 2048 + 192) { W = Wqkv; Wt = wqkvt; K = 512; N = 1536; tb = b - 2048; }
  else               { W = Wout; Wt = woutt; K = 512; N = 512;  tb = b - 2240; }
  int nb = N >> 6;
  int tn = tb % nb, tk = tb / nb;
  int n0 = tn << 6, k0 = tk << 6;
  int cr = tid >> 4, cc = (tid & 15) << 2;
#pragma unroll
  for (int i = 0; i < 4; i++) {
    int r = cr + (i << 4);
    f32x4 v = *(const f32x4*)(W + (size_t)(k0 + r) * N + n0 + cc);
    t[r][cc] = v[0]; t[r][cc + 1] = v[1]; t[r][cc + 2] = v[2]; t[r][cc + 3] = v[3];
  }
  __syncthreads();
#pragma unroll
  for (int i = 0; i < 4; i++) {
    int nn = cr + (i << 4);
    s16x4 o;
    o[0] = (short)f2bf(t[cc    ][nn]);
    o[1] = (short)f2bf(t[cc + 1][nn]);
    o[2] = (short)f2bf(t[cc + 2][nn]);
    o[3] = (short)f2bf(t[cc + 3][nn]);
    *(s16x4*)(Wt + (size_t)(n0 + nn) * K + k0 + cc) = o;
  }
}

// ------------------------------------------------------------------ GEMM1
// r4 K-loop (best measured, frozen). Epilogue: q direct (+phi) to
// qphi[bh][tok][d]; k/v transposed s16x4 stores to kphiT/vT [bh][d][tok].
__global__ __launch_bounds__(512, 1) void k_gemm1(
    const u16* __restrict__ A, const u16* __restrict__ Bt,
    u16* __restrict__ qph, u16* __restrict__ kphT, u16* __restrict__ vT) {
  __shared__ __align__(16) u16 lsA[3][256 * 32];
  __shared__ __align__(16) u16 lsB[3][256 * 32];
  const int nbn = 6;
  int nwg = gridDim.x;
  int bx = blockIdx.x;
  int o = (bx & 7) * (nwg >> 3) + (bx >> 3);
  int bm = o / nbn, bn = o % nbn;
  int m0 = bm << 8, n0 = bn << 8;
  int tid = threadIdx.x;
  int w = tid >> 6, lane = tid & 63;
  int lnlo = lane & 15, lnhi = lane >> 4;
  int wr = w >> 2, wc = w & 3;

  const u16* gAp[2]; const u16* gBp[2]; int ldst[2];
#pragma unroll
  for (int i = 0; i < 2; i++) {
    int c = tid + i * 512;
    int row = c >> 2, ch = c & 3;
    int gch = ch ^ ((row >> 1) & 3);
    gAp[i] = A + (size_t)(m0 + row) * 512 + gch * 8;
    gBp[i] = Bt + (size_t)(n0 + row) * 512 + gch * 8;
    ldst[i] = c * 8;
  }
  int offA[8], offB[4];
#pragma unroll
  for (int f = 0; f < 8; f++) {
    int r = wr * 128 + f * 16 + lnlo;
    offA[f] = r * 32 + (lnhi ^ ((r >> 1) & 3)) * 8;
  }
#pragma unroll
  for (int f = 0; f < 4; f++) {
    int r = wc * 64 + f * 16 + lnlo;
    offB[f] = r * 32 + (lnhi ^ ((r >> 1) & 3)) * 8;
  }

  f32x4 acc[8][4] = {};

#pragma unroll
  for (int i = 0; i < 2; i++) gload16(gAp[i], &lsA[0][ldst[i]]);
#pragma unroll
  for (int i = 0; i < 2; i++) gload16(gBp[i], &lsB[0][ldst[i]]);
#pragma unroll
  for (int i = 0; i < 2; i++) gload16(gAp[i] + 32, &lsA[1][ldst[i]]);
#pragma unroll
  for (int i = 0; i < 2; i++) gload16(gBp[i] + 32, &lsB[1][ldst[i]]);
  asm volatile("s_waitcnt vmcnt(4)" ::: "memory");
  __builtin_amdgcn_s_barrier();

#pragma unroll
  for (int t = 0; t < 16; t++) {
    int buf = t % 3;
    const u16* La = &lsA[buf][0];
    const u16* Lb = &lsB[buf][0];
    int k2 = (t + 2) * 32;
    int b2 = (t + 2) % 3;

    s16x8 bf[4], af[4];
#pragma unroll
    for (int f = 0; f < 4; f++) bf[f] = *(const s16x8*)(Lb + offB[f]);
#pragma unroll
    for (int f = 0; f < 4; f++) af[f] = *(const s16x8*)(La + offA[f]);
    if (t < 14) {
#pragma unroll
      for (int i = 0; i < 2; i++) gload16(gAp[i] + k2, &lsA[b2][ldst[i]]);
    }
    __builtin_amdgcn_s_barrier();
    __builtin_amdgcn_s_setprio(1);
#pragma unroll
    for (int mf = 0; mf < 4; mf++)
#pragma unroll
      for (int nf = 0; nf < 4; nf++)
        acc[mf][nf] = __builtin_amdgcn_mfma_f32_16x16x32_bf16(af[mf], bf[nf], acc[mf][nf], 0, 0, 0);
    __builtin_amdgcn_s_setprio(0);
    __builtin_amdgcn_s_barrier();

    s16x8 af2[4];
#pragma unroll
    for (int f = 0; f < 4; f++) af2[f] = *(const s16x8*)(La + offA[4 + f]);
    if (t < 14) {
#pragma unroll
      for (int i = 0; i < 2; i++) gload16(gBp[i] + k2, &lsB[b2][ldst[i]]);
    }
    __builtin_amdgcn_s_barrier();
    __builtin_amdgcn_s_setprio(1);
#pragma unroll
    for (int mf = 0; mf < 4; mf++)
#pragma unroll
      for (int nf = 0; nf < 4; nf++)
        acc[4 + mf][nf] = __builtin_amdgcn_mfma_f32_16x16x32_bf16(af2[mf], bf[nf], acc[4 + mf][nf], 0, 0, 0);
    __builtin_amdgcn_s_setprio(0);
    if (t <= 13)      asm volatile("s_waitcnt vmcnt(4)" ::: "memory");
    else if (t == 14) asm volatile("s_waitcnt vmcnt(0)" ::: "memory");
    if (t < 15) __builtin_amdgcn_s_barrier();
  }

  int gmB = m0 + wr * 128;
  int gnB = n0 + wc * 64;
  int sec = n0 >> 9;
  if (sec == 0) {
#pragma unroll
    for (int mf = 0; mf < 8; mf++) {
#pragma unroll
      for (int nf = 0; nf < 4; nf++) {
        int col = gnB + nf * 16 + lnlo;
        int hh = (col >> 6) & 7;
        int dd = col & 63;
#pragma unroll
        for (int r = 0; r < 4; r++) {
          int rowm = gmB + mf * 16 + lnhi * 4 + r;
          float val = acc[mf][nf][r];
          val = (val > 0.f) ? (val + 1.f) : __expf(val);  // elu+1
          int bidx = rowm >> 12, tok = rowm & 4095;
          qph[(((size_t)(bidx * 8 + hh) * 4096 + tok) << 6) + dd] = f2bf(val);
        }
      }
    }
  } else {
    u16* dstT = (sec == 1) ? kphT : vT;    // [bh][d=64][n=4096]
    bool isphi = (sec == 1);
#pragma unroll
    for (int mf = 0; mf < 8; mf++) {
      int rowm = gmB + mf * 16 + lnhi * 4;
      int bidx = rowm >> 12, tok = rowm & 4095;
#pragma unroll
      for (int nf = 0; nf < 4; nf++) {
        int col = gnB + nf * 16 + lnlo;
        int hh = (col >> 6) & 7;
        int dd = col & 63;
        s16x4 o4;
#pragma unroll
        for (int r = 0; r < 4; r++) {
          float val = acc[mf][nf][r];
          if (isphi) val = (val > 0.f) ? (val + 1.f) : __expf(val);
          o4[r] = (short)f2bf(val);
        }
        *(s16x4*)&dstT[((size_t)(bidx * 8 + hh) * 64 + dd) * 4096 + tok] = o4;
      }
    }
  }
}

// -------------------------------------------- KV partials via MFMA + Ksum
__global__ __launch_bounds__(256, 2) void k_kv(const u16* __restrict__ kphT,
                                               const u16* __restrict__ vT,
                                               float* __restrict__ kvpart,
                                               float* __restrict__ kspart) {
  __shared__ __align__(16) u16 lsK[64 * 256];
  __shared__ __align__(16) u16 lsV[64 * 256];
  __shared__ float red[4][64];
  int bx = blockIdx.x;
  int bh = bx >> 4, ck = bx & 15;
  int tid = threadIdx.x, w = tid >> 6, lane = tid & 63;
  int lnlo = lane & 15, lnhi = lane >> 4;
  size_t gbase = (size_t)bh * 64 * 4096 + ck * 256;

#pragma unroll
  for (int i = 0; i < 8; i++) {
    int c = tid + i * 256;
    int row = c >> 5, ch = c & 31;
    int gch = ch ^ (row & 31);
    gload16(kphT + gbase + (size_t)row * 4096 + gch * 8, &lsK[c * 8]);
  }
#pragma unroll
  for (int i = 0; i < 8; i++) {
    int c = tid + i * 256;
    int row = c >> 5, ch = c & 31;
    int gch = ch ^ (row & 31);
    gload16(vT + gbase + (size_t)row * 4096 + gch * 8, &lsV[c * 8]);
  }
  asm volatile("s_waitcnt vmcnt(0)" ::: "memory");
  __builtin_amdgcn_s_barrier();

  f32x4 acc[4] = {{0.f, 0.f, 0.f, 0.f}, {0.f, 0.f, 0.f, 0.f},
                  {0.f, 0.f, 0.f, 0.f}, {0.f, 0.f, 0.f, 0.f}};
  int rb = w * 16 + lnlo;
#pragma unroll
  for (int kk = 0; kk < 8; kk++) {
    s16x8 bfr = *(const s16x8*)&lsV[rb * 256 + ((kk * 4 + lnhi) ^ (rb & 31)) * 8];
#pragma unroll
    for (int mf = 0; mf < 4; mf++) {
      int ra = mf * 16 + lnlo;
      s16x8 af = *(const s16x8*)&lsK[ra * 256 + ((kk * 4 + lnhi) ^ (ra & 31)) * 8];
      acc[mf] = __builtin_amdgcn_mfma_f32_16x16x32_bf16(af, bfr, acc[mf], 0, 0, 0);
    }
  }

  {
    int d = tid & 63, q = tid >> 6;
    float s = 0.f;
#pragma unroll
    for (int j = 0; j < 8; j++) {
      s16x8 v8 = *(const s16x8*)&lsK[d * 256 + (q * 8 + j) * 8];
#pragma unroll
      for (int e = 0; e < 8; e++) s += bf2f((u16)v8[e]);
    }
    red[q][d] = s;
  }
  __syncthreads();

  size_t pb = (size_t)(bh * 16 + ck) * 4096;
#pragma unroll
  for (int mf = 0; mf < 4; mf++)
#pragma unroll
    for (int r = 0; r < 4; r++)
      kvpart[pb + (size_t)(mf * 16 + lnhi * 4 + r) * 64 + (w * 16 + lnlo)] = acc[mf][r];
  if (tid < 64)
    kspart[(size_t)(bh * 16 + ck) * 64 + tid] =
        red[0][tid] + red[1][tid] + red[2][tid] + red[3][tid];
}

// ---------------------------------------------- W2 + scaled qphi
// blocks [0,64): bh -> W2T[b][n][h*64+d] = (reduce kvpart) @ woutt
// blocks [64,576): (bh, tok-chunk) -> qphs[bh][tok][d] = qphi*rdn (bf16)
__global__ __launch_bounds__(256) void k_w2(const float* __restrict__ kvpart,
                                            const float* __restrict__ kspart,
                                            const u16* __restrict__ woutt,
                                            const u16* __restrict__ qphi,
                                            u16* __restrict__ w2t,
                                            u16* __restrict__ qphs) {
  __shared__ __align__(16) u16 kvls[64 * 64];
  __shared__ float ksumv[64];
  int blk = blockIdx.x, tid = threadIdx.x;
  if (blk < 64) {
    int bh = blk, b = bh >> 3, h = bh & 7;
    int w = tid >> 6, lane = tid & 63, lnlo = lane & 15, lnhi = lane >> 4;
    int d = tid >> 2, e0 = (tid & 3) << 4;
    size_t pb = (size_t)bh * 16 * 4096;
    f32x4 s0 = {}, s1 = {}, s2 = {}, s3 = {};
    for (int c = 0; c < 16; c++) {
      const float* p = kvpart + pb + (size_t)c * 4096 + d * 64 + e0;
      s0 += *(const f32x4*)(p);
      s1 += *(const f32x4*)(p + 4);
      s2 += *(const f32x4*)(p + 8);
      s3 += *(const f32x4*)(p + 12);
    }
    s16x8 o0, o1;
#pragma unroll
    for (int j = 0; j < 4; j++) {
      o0[j] = (short)f2bf(s0[j]); o0[4 + j] = (short)f2bf(s1[j]);
      o1[j] = (short)f2bf(s2[j]); o1[4 + j] = (short)f2bf(s3[j]);
    }
    int ch0 = e0 >> 3;
    *(s16x8*)&kvls[d * 64 + (ch0 ^ (d & 7)) * 8] = o0;
    *(s16x8*)&kvls[d * 64 + ((ch0 + 1) ^ (d & 7)) * 8] = o1;
    __syncthreads();
    f32x4 acc[4][8] = {};
#pragma unroll
    for (int kk = 0; kk < 2; kk++) {
      s16x8 af[4], bfr[8];
#pragma unroll
      for (int mf = 0; mf < 4; mf++) {
        int r = mf * 16 + lnlo;
        af[mf] = *(const s16x8*)&kvls[r * 64 + ((kk * 4 + lnhi) ^ (r & 7)) * 8];
      }
#pragma unroll
      for (int nf = 0; nf < 8; nf++) {
        int n = w * 128 + nf * 16 + lnlo;
        bfr[nf] = *(const s16x8*)&woutt[(size_t)n * 512 + h * 64 + (kk * 4 + lnhi) * 8];
      }
#pragma unroll
      for (int mf = 0; mf < 4; mf++)
#pragma unroll
        for (int nf = 0; nf < 8; nf++)
          acc[mf][nf] = __builtin_amdgcn_mfma_f32_16x16x32_bf16(af[mf], bfr[nf], acc[mf][nf], 0, 0, 0);
    }
#pragma unroll
    for (int mf = 0; mf < 4; mf++)
#pragma unroll
      for (int nf = 0; nf < 8; nf++) {
        int n = w * 128 + nf * 16 + lnlo;
        s16x4 o4;
#pragma unroll
        for (int r = 0; r < 4; r++) o4[r] = (short)f2bf(acc[mf][nf][r]);
        *(s16x4*)&w2t[(size_t)b * 262144 + (size_t)n * 512 + h * 64 + mf * 16 + lnhi * 4] = o4;
      }
  } else {
    int blk2 = blk - 64;
    int bh = blk2 >> 3, tch = blk2 & 7;
    if (tid < 64) {
      float s = 0.f;
#pragma unroll
      for (int c = 0; c < 16; c++) s += kspart[(size_t)bh * 1024 + c * 64 + tid];
      ksumv[tid] = s;
    }
    __syncthreads();
#pragma unroll
    for (int tt = 0; tt < 2; tt++) {
      int tok = tch * 512 + tt * 256 + tid;
      const u16* qp = qphi + ((size_t)bh * 4096 + tok) * 64;
      s16x8 v8[8];
      float den = 0.f;
#pragma unroll
      for (int cch = 0; cch < 8; cch++) {
        v8[cch] = *(const s16x8*)(qp + cch * 8);
#pragma unroll
        for (int j = 0; j < 8; j++) den += bf2f((u16)v8[cch][j]) * ksumv[cch * 8 + j];
      }
      float rdn = 1.f / (den + 1e-6f);
      u16* qd = qphs + ((size_t)bh * 4096 + tok) * 64;
#pragma unroll
      for (int cch = 0; cch < 8; cch++) {
        s16x8 oo;
#pragma unroll
        for (int j = 0; j < 8; j++) oo[j] = (short)f2bf(bf2f((u16)v8[cch][j]) * rdn);
        *(s16x8*)(qd + cch * 8) = oo;
      }
    }
  }
}

// ----------------------------------------------------------------- k_out
// out[m][n] = qphs_gather[m][k] @ W2T[b][n][k] + bias[n].
// r4 K-loop structure (512 thr, 256x256, BK=32, 3-buf, counted vmcnt);
// A staged via gload_lds with per-h-plane gathered addresses (k-tile t ->
// h = t>>1, intra-plane off = (t&1)*32); no reg-staging (qphs pre-scaled).
__global__ __launch_bounds__(512, 1) void k_out(
    const u16* __restrict__ qphs, const u16* __restrict__ w2t,
    const float* __restrict__ bias, float* __restrict__ out) {
  __shared__ __align__(16) u16 lsA[3][256 * 32];
  __shared__ __align__(16) u16 lsB[3][256 * 32];
  const int nbn = 2;
  int nwg = gridDim.x, bx = blockIdx.x;
  int o = (bx & 7) * (nwg >> 3) + (bx >> 3);   // 256%8==0
  int bm = o / nbn, bn = o % nbn;
  int m0 = bm << 8, n0 = bn << 8;
  int b = m0 >> 12;
  int tid = threadIdx.x, w = tid >> 6, lane = tid & 63;
  int lnlo = lane & 15, lnhi = lane >> 4;
  int wr = w >> 2, wc = w & 3;

  const u16* qb_[2]; const u16* gBp[2]; int ldst[2];
#pragma unroll
  for (int i = 0; i < 2; i++) {
    int c = tid + i * 512, row = c >> 2, ch = c & 3;
    int gch = ch ^ ((row >> 1) & 3);
    int tok = (m0 + row) & 4095;
    qb_[i] = qphs + ((size_t)(b * 8) * 4096 + tok) * 64 + gch * 8;
    gBp[i] = w2t + (size_t)b * 262144 + (size_t)(n0 + row) * 512 + gch * 8;
    ldst[i] = c * 8;
  }
  int offA[8], offB[4];
#pragma unroll
  for (int f = 0; f < 8; f++) {
    int r = wr * 128 + f * 16 + lnlo;
    offA[f] = r * 32 + (lnhi ^ ((r >> 1) & 3)) * 8;
  }
#pragma unroll
  for (int f = 0; f < 4; f++) {
    int r = wc * 64 + f * 16 + lnlo;
    offB[f] = r * 32 + (lnhi ^ ((r >> 1) & 3)) * 8;
  }

  f32x4 acc[8][4] = {};

  auto stageA = [&](int t, int buf) {
    size_t hoff = (size_t)(t >> 1) * 262144 + (t & 1) * 32;
#pragma unroll
    for (int i = 0; i < 2; i++) gload16(qb_[i] + hoff, &lsA[buf][ldst[i]]);
  };
  auto stageB = [&](int t, int buf) {
#pragma unroll
    for (int i = 0; i < 2; i++) gload16(gBp[i] + t * 32, &lsB[buf][ldst[i]]);
  };

  stageA(0, 0); stageB(0, 0);
  stageA(1, 1); stageB(1, 1);
  asm volatile("s_waitcnt vmcnt(4)" ::: "memory");
  __builtin_amdgcn_s_barrier();

#pragma unroll
  for (int t = 0; t < 16; t++) {
    int buf = t % 3;
    const u16* La = &lsA[buf][0];
    const u16* Lb = &lsB[buf][0];
    int b2 = (t + 2) % 3;

    s16x8 bf[4], af[4];
#pragma unroll
    for (int f = 0; f < 4; f++) bf[f] = *(const s16x8*)(Lb + offB[f]);
#pragma unroll
    for (int f = 0; f < 4; f++) af[f] = *(const s16x8*)(La + offA[f]);
    if (t < 14) stageA(t + 2, b2);
    __builtin_amdgcn_s_barrier();
    __builtin_amdgcn_s_setprio(1);
#pragma unroll
    for (int mf = 0; mf < 4; mf++)
#pragma unroll
      for (int nf = 0; nf < 4; nf++)
        acc[mf][nf] = __builtin_amdgcn_mfma_f32_16x16x32_bf16(af[mf], bf[nf], acc[mf][nf], 0, 0, 0);
    __builtin_amdgcn_s_setprio(0);
    __builtin_amdgcn_s_barrier();

    s16x8 af2[4];
#pragma unroll
    for (int f = 0; f < 4; f++) af2[f] = *(const s16x8*)(La + offA[4 + f]);
    if (t < 14) stageB(t + 2, b2);
    __builtin_amdgcn_s_barrier();
    __builtin_amdgcn_s_setprio(1);
#pragma unroll
    for (int mf = 0; mf < 4; mf++)
#pragma unroll
      for (int nf = 0; nf < 4; nf++)
        acc[4 + mf][nf] = __builtin_amdgcn_mfma_f32_16x16x32_bf16(af2[mf], bf[nf], acc[4 + mf][nf], 0, 0, 0);
    __builtin_amdgcn_s_setprio(0);
    if (t <= 13)      asm volatile("s_waitcnt vmcnt(4)" ::: "memory");
    else if (t == 14) asm volatile("s_waitcnt vmcnt(0)" ::: "memory");
    if (t < 15) __builtin_amdgcn_s_barrier();
  }

  int gmB = m0 + wr * 128;
  int gnB = n0 + wc * 64;
#pragma unroll
  for (int mf = 0; mf < 8; mf++) {
#pragma unroll
    for (int nf = 0; nf < 4; nf++) {
      int col = gnB + nf * 16 + lnlo;
      float bv = bias[col];
#pragma unroll
      for (int r = 0; r < 4; r++) {
        int rowm = gmB + mf * 16 + lnhi * 4 + r;
        out[(size_t)rowm * 512 + col] = acc[mf][nf][r] + bv;
      }
    }
  }
}

// ------------------------------------------------------------------ launch
#define OFF_XB     ((size_t)0)             // 33.5MB xb; after GEMM1: w2t
#define OFF_W2T    ((size_t)0)             //  4,194,304 (alias xb)
#define OFF_WQKVT  ((size_t)33554432)      //  1,572,864
#define OFF_WOUTT  ((size_t)35127296)      //    524,288
#define OFF_QPHI   ((size_t)35651584)      // 33,554,432
#define OFF_KPHI   ((size_t)69206016)      // 33,554,432 (kphiT; later qphs)
#define OFF_VBUF   ((size_t)102760448)     // 33,554,432 (vT [bh][64][4096])
#define OFF_KVPART ((size_t)136314880)     // 16,777,216
#define OFF_KSPART ((size_t)153092096)     //    262,144

extern "C" void kernel_launch(void* const* d_in, const int* in_sizes, int n_in,
                              void* d_out, int out_size, void* d_ws, size_t ws_size,
                              hipStream_t stream) {
  const float* x    = (const float*)d_in[0];
  const float* Wqkv = (const float*)d_in[1];
  const float* Wout = (const float*)d_in[2];
  const float* bout = (const float*)d_in[3];
  float* out = (float*)d_out;
  char* ws = (char*)d_ws;

  u16* xb     = (u16*)(ws + OFF_XB);
  u16* w2t    = (u16*)(ws + OFF_W2T);    // alias: xb dead after GEMM1
  u16* wqkvt  = (u16*)(ws + OFF_WQKVT);
  u16* woutt  = (u16*)(ws + OFF_WOUTT);
  u16* qphi   = (u16*)(ws + OFF_QPHI);
  u16* kphT   = (u16*)(ws + OFF_KPHI);
  u16* qphs   = (u16*)(ws + OFF_KPHI);   // alias: kphT dead after k_kv
  u16* vT     = (u16*)(ws + OFF_VBUF);
  float* kvpart = (float*)(ws + OFF_KVPART);
  float* kspart = (float*)(ws + OFF_KSPART);

  k_prep<<<2304, 256, 0, stream>>>(x, xb, Wqkv, wqkvt, Wout, woutt);
  // qkv = xb @ Wqkv. 128 Mtiles x 6 Ntiles = 768 blocks.
  k_gemm1<<<768, 512, 0, stream>>>(xb, wqkvt, qphi, kphT, vT);
  k_kv<<<1024, 256, 0, stream>>>(kphT, vT, kvpart, kspart);
  k_w2<<<576, 256, 0, stream>>>(kvpart, kspart, woutt, qphi, w2t, qphs);
  // out = qphs @ W2T + b. 128 Mtiles x 2 Ntiles = 256 blocks.
  k_out<<<256, 512, 0, stream>>>(qphs, w2t, bout, out);
}

// Round 14
// 153.453 us; speedup vs baseline: 1.0613x; 1.0265x over previous
//
#include <hip/hip_runtime.h>
#include <stdint.h>

typedef float    f32x4 __attribute__((ext_vector_type(4)));
typedef short    s16x8 __attribute__((ext_vector_type(8)));
typedef short    s16x4 __attribute__((ext_vector_type(4)));
typedef unsigned short u16;
typedef uint32_t u32;

#define DEVINL __device__ __forceinline__

DEVINL float bf2f(u16 u) { union { u32 i; float f; } x; x.i = ((u32)u) << 16; return x.f; }
DEVINL u16 f2bf(float f) {
  union { float f; u32 i; } x; x.f = f;
  u32 i = x.i;
  return (u16)((i + 0x7FFFu + ((i >> 16) & 1u)) >> 16);  // RNE
}

DEVINL void gload16(const void* g, void* l) {
  __builtin_amdgcn_global_load_lds((const __attribute__((address_space(1))) void*)g,
                                   (__attribute__((address_space(3))) void*)l,
                                   16, 0, 0);
}

// --------------------------- prep: conv x->bf16 + both weight transposes
__global__ __launch_bounds__(256) void k_prep(const float* __restrict__ x,
                                              u16* __restrict__ xb,
                                              const float* __restrict__ Wqkv,
                                              u16* __restrict__ wqkvt,
                                              const float* __restrict__ Wout,
                                              u16* __restrict__ woutt) {
  __shared__ __align__(16) float t[64][65];
  int b = blockIdx.x;
  int tid = threadIdx.x;
  if (b < 2048) {
    const int n8 = 2097152;
    int stride = 2048 * 256;
    for (int i = b * 256 + tid; i < n8; i += stride) {
      const f32x4* p = (const f32x4*)(x + (size_t)i * 8);
      f32x4 a = p[0], c = p[1];
      s16x8 o;
      o[0] = (short)f2bf(a[0]); o[1] = (short)f2bf(a[1]);
      o[2] = (short)f2bf(a[2]); o[3] = (short)f2bf(a[3]);
      o[4] = (short)f2bf(c[0]); o[5] = (short)f2bf(c[1]);
      o[6] = (short)f2bf(c[2]); o[7] = (short)f2bf(c[3]);
      *(s16x8*)(xb + (size_t)i * 8) = o;
    }
    return;
  }
  const float* W; u16* Wt; int K, N, tb;
  if (b < 2048 + 192) { W = Wqkv; Wt = wqkvt; K = 512; N = 1536; tb = b - 2048; }
  else               { W = Wout; Wt = woutt; K = 512; N = 512;  tb = b - 2240; }
  int nb = N >> 6;
  int tn = tb % nb, tk = tb / nb;
  int n0 = tn << 6, k0 = tk << 6;
  int cr = tid >> 4, cc = (tid & 15) << 2;
#pragma unroll
  for (int i = 0; i < 4; i++) {
    int r = cr + (i << 4);
    f32x4 v = *(const f32x4*)(W + (size_t)(k0 + r) * N + n0 + cc);
    t[r][cc] = v[0]; t[r][cc + 1] = v[1]; t[r][cc + 2] = v[2]; t[r][cc + 3] = v[3];
  }
  __syncthreads();
#pragma unroll
  for (int i = 0; i < 4; i++) {
    int nn = cr + (i << 4);
    s16x4 o;
    o[0] = (short)f2bf(t[cc    ][nn]);
    o[1] = (short)f2bf(t[cc + 1][nn]);
    o[2] = (short)f2bf(t[cc + 2][nn]);
    o[3] = (short)f2bf(t[cc + 3][nn]);
    *(s16x4*)(Wt + (size_t)(n0 + nn) * K + k0 + cc) = o;
  }
}

// ------------------------------------------------------------------ GEMM1
// r4 K-loop (best measured, frozen). Epilogue: q direct (+phi) to
// qphi[bh][tok][d]; k/v transposed s16x4 stores to kphiT/vT [bh][d][tok].
__global__ __launch_bounds__(512, 1) void k_gemm1(
    const u16* __restrict__ A, const u16* __restrict__ Bt,
    u16* __restrict__ qph, u16* __restrict__ kphT, u16* __restrict__ vT) {
  __shared__ __align__(16) u16 lsA[3][256 * 32];
  __shared__ __align__(16) u16 lsB[3][256 * 32];
  const int nbn = 6;
  int nwg = gridDim.x;
  int bx = blockIdx.x;
  int o = (bx & 7) * (nwg >> 3) + (bx >> 3);
  int bm = o / nbn, bn = o % nbn;
  int m0 = bm << 8, n0 = bn << 8;
  int tid = threadIdx.x;
  int w = tid >> 6, lane = tid & 63;
  int lnlo = lane & 15, lnhi = lane >> 4;
  int wr = w >> 2, wc = w & 3;

  const u16* gAp[2]; const u16* gBp[2]; int ldst[2];
#pragma unroll
  for (int i = 0; i < 2; i++) {
    int c = tid + i * 512;
    int row = c >> 2, ch = c & 3;
    int gch = ch ^ ((row >> 1) & 3);
    gAp[i] = A + (size_t)(m0 + row) * 512 + gch * 8;
    gBp[i] = Bt + (size_t)(n0 + row) * 512 + gch * 8;
    ldst[i] = c * 8;
  }
  int offA[8], offB[4];
#pragma unroll
  for (int f = 0; f < 8; f++) {
    int r = wr * 128 + f * 16 + lnlo;
    offA[f] = r * 32 + (lnhi ^ ((r >> 1) & 3)) * 8;
  }
#pragma unroll
  for (int f = 0; f < 4; f++) {
    int r = wc * 64 + f * 16 + lnlo;
    offB[f] = r * 32 + (lnhi ^ ((r >> 1) & 3)) * 8;
  }

  f32x4 acc[8][4] = {};

#pragma unroll
  for (int i = 0; i < 2; i++) gload16(gAp[i], &lsA[0][ldst[i]]);
#pragma unroll
  for (int i = 0; i < 2; i++) gload16(gBp[i], &lsB[0][ldst[i]]);
#pragma unroll
  for (int i = 0; i < 2; i++) gload16(gAp[i] + 32, &lsA[1][ldst[i]]);
#pragma unroll
  for (int i = 0; i < 2; i++) gload16(gBp[i] + 32, &lsB[1][ldst[i]]);
  asm volatile("s_waitcnt vmcnt(4)" ::: "memory");
  __builtin_amdgcn_s_barrier();

#pragma unroll
  for (int t = 0; t < 16; t++) {
    int buf = t % 3;
    const u16* La = &lsA[buf][0];
    const u16* Lb = &lsB[buf][0];
    int k2 = (t + 2) * 32;
    int b2 = (t + 2) % 3;

    s16x8 bf[4], af[4];
#pragma unroll
    for (int f = 0; f < 4; f++) bf[f] = *(const s16x8*)(Lb + offB[f]);
#pragma unroll
    for (int f = 0; f < 4; f++) af[f] = *(const s16x8*)(La + offA[f]);
    if (t < 14) {
#pragma unroll
      for (int i = 0; i < 2; i++) gload16(gAp[i] + k2, &lsA[b2][ldst[i]]);
    }
    __builtin_amdgcn_s_barrier();
    __builtin_amdgcn_s_setprio(1);
#pragma unroll
    for (int mf = 0; mf < 4; mf++)
#pragma unroll
      for (int nf = 0; nf < 4; nf++)
        acc[mf][nf] = __builtin_amdgcn_mfma_f32_16x16x32_bf16(af[mf], bf[nf], acc[mf][nf], 0, 0, 0);
    __builtin_amdgcn_s_setprio(0);
    __builtin_amdgcn_s_barrier();

    s16x8 af2[4];
#pragma unroll
    for (int f = 0; f < 4; f++) af2[f] = *(const s16x8*)(La + offA[4 + f]);
    if (t < 14) {
#pragma unroll
      for (int i = 0; i < 2; i++) gload16(gBp[i] + k2, &lsB[b2][ldst[i]]);
    }
    __builtin_amdgcn_s_barrier();
    __builtin_amdgcn_s_setprio(1);
#pragma unroll
    for (int mf = 0; mf < 4; mf++)
#pragma unroll
      for (int nf = 0; nf < 4; nf++)
        acc[4 + mf][nf] = __builtin_amdgcn_mfma_f32_16x16x32_bf16(af2[mf], bf[nf], acc[4 + mf][nf], 0, 0, 0);
    __builtin_amdgcn_s_setprio(0);
    if (t <= 13)      asm volatile("s_waitcnt vmcnt(4)" ::: "memory");
    else if (t == 14) asm volatile("s_waitcnt vmcnt(0)" ::: "memory");
    if (t < 15) __builtin_amdgcn_s_barrier();
  }

  int gmB = m0 + wr * 128;
  int gnB = n0 + wc * 64;
  int sec = n0 >> 9;
  if (sec == 0) {
#pragma unroll
    for (int mf = 0; mf < 8; mf++) {
#pragma unroll
      for (int nf = 0; nf < 4; nf++) {
        int col = gnB + nf * 16 + lnlo;
        int hh = (col >> 6) & 7;
        int dd = col & 63;
#pragma unroll
        for (int r = 0; r < 4; r++) {
          int rowm = gmB + mf * 16 + lnhi * 4 + r;
          float val = acc[mf][nf][r];
          val = (val > 0.f) ? (val + 1.f) : __expf(val);  // elu+1
          int bidx = rowm >> 12, tok = rowm & 4095;
          qph[(((size_t)(bidx * 8 + hh) * 4096 + tok) << 6) + dd] = f2bf(val);
        }
      }
    }
  } else {
    u16* dstT = (sec == 1) ? kphT : vT;    // [bh][d=64][n=4096]
    bool isphi = (sec == 1);
#pragma unroll
    for (int mf = 0; mf < 8; mf++) {
      int rowm = gmB + mf * 16 + lnhi * 4;
      int bidx = rowm >> 12, tok = rowm & 4095;
#pragma unroll
      for (int nf = 0; nf < 4; nf++) {
        int col = gnB + nf * 16 + lnlo;
        int hh = (col >> 6) & 7;
        int dd = col & 63;
        s16x4 o4;
#pragma unroll
        for (int r = 0; r < 4; r++) {
          float val = acc[mf][nf][r];
          if (isphi) val = (val > 0.f) ? (val + 1.f) : __expf(val);
          o4[r] = (short)f2bf(val);
        }
        *(s16x4*)&dstT[((size_t)(bidx * 8 + hh) * 64 + dd) * 4096 + tok] = o4;
      }
    }
  }
}

// -------------------------------------------- KV partials via MFMA + Ksum
__global__ __launch_bounds__(256, 2) void k_kv(const u16* __restrict__ kphT,
                                               const u16* __restrict__ vT,
                                               float* __restrict__ kvpart,
                                               float* __restrict__ kspart) {
  __shared__ __align__(16) u16 lsK[64 * 256];
  __shared__ __align__(16) u16 lsV[64 * 256];
  __shared__ float red[4][64];
  int bx = blockIdx.x;
  int bh = bx >> 4, ck = bx & 15;
  int tid = threadIdx.x, w = tid >> 6, lane = tid & 63;
  int lnlo = lane & 15, lnhi = lane >> 4;
  size_t gbase = (size_t)bh * 64 * 4096 + ck * 256;

#pragma unroll
  for (int i = 0; i < 8; i++) {
    int c = tid + i * 256;
    int row = c >> 5, ch = c & 31;
    int gch = ch ^ (row & 31);
    gload16(kphT + gbase + (size_t)row * 4096 + gch * 8, &lsK[c * 8]);
  }
#pragma unroll
  for (int i = 0; i < 8; i++) {
    int c = tid + i * 256;
    int row = c >> 5, ch = c & 31;
    int gch = ch ^ (row & 31);
    gload16(vT + gbase + (size_t)row * 4096 + gch * 8, &lsV[c * 8]);
  }
  asm volatile("s_waitcnt vmcnt(0)" ::: "memory");
  __builtin_amdgcn_s_barrier();

  f32x4 acc[4] = {{0.f, 0.f, 0.f, 0.f}, {0.f, 0.f, 0.f, 0.f},
                  {0.f, 0.f, 0.f, 0.f}, {0.f, 0.f, 0.f, 0.f}};
  int rb = w * 16 + lnlo;
#pragma unroll
  for (int kk = 0; kk < 8; kk++) {
    s16x8 bfr = *(const s16x8*)&lsV[rb * 256 + ((kk * 4 + lnhi) ^ (rb & 31)) * 8];
#pragma unroll
    for (int mf = 0; mf < 4; mf++) {
      int ra = mf * 16 + lnlo;
      s16x8 af = *(const s16x8*)&lsK[ra * 256 + ((kk * 4 + lnhi) ^ (ra & 31)) * 8];
      acc[mf] = __builtin_amdgcn_mfma_f32_16x16x32_bf16(af, bfr, acc[mf], 0, 0, 0);
    }
  }

  {
    int d = tid & 63, q = tid >> 6;
    float s = 0.f;
#pragma unroll
    for (int j = 0; j < 8; j++) {
      s16x8 v8 = *(const s16x8*)&lsK[d * 256 + (q * 8 + j) * 8];
#pragma unroll
      for (int e = 0; e < 8; e++) s += bf2f((u16)v8[e]);
    }
    red[q][d] = s;
  }
  __syncthreads();

  size_t pb = (size_t)(bh * 16 + ck) * 4096;
#pragma unroll
  for (int mf = 0; mf < 4; mf++)
#pragma unroll
    for (int r = 0; r < 4; r++)
      kvpart[pb + (size_t)(mf * 16 + lnhi * 4 + r) * 64 + (w * 16 + lnlo)] = acc[mf][r];
  if (tid < 64)
    kspart[(size_t)(bh * 16 + ck) * 64 + tid] =
        red[0][tid] + red[1][tid] + red[2][tid] + red[3][tid];
}

// ---------------------------------------------- W2 + per-head reciprocals
// blocks [0,64): bh -> W2T[b][n][h*64+d] = (reduce kvpart)[d][e] @ woutt rows
// blocks [64,576): (bh, tok-chunk) -> rdn[bh][tok] = 1/(qphi.ksum + eps)
__global__ __launch_bounds__(256) void k_w2(const float* __restrict__ kvpart,
                                            const float* __restrict__ kspart,
                                            const u16* __restrict__ woutt,
                                            const u16* __restrict__ qphi,
                                            u16* __restrict__ w2t,
                                            float* __restrict__ rdng) {
  __shared__ __align__(16) u16 kvls[64 * 64];
  __shared__ float ksumv[64];
  int blk = blockIdx.x, tid = threadIdx.x;
  if (blk < 64) {
    int bh = blk, b = bh >> 3, h = bh & 7;
    int w = tid >> 6, lane = tid & 63, lnlo = lane & 15, lnhi = lane >> 4;
    // reduce kvpart -> KV bf16 (swizzled ch^(d&7))
    int d = tid >> 2, e0 = (tid & 3) << 4;
    size_t pb = (size_t)bh * 16 * 4096;
    f32x4 s0 = {}, s1 = {}, s2 = {}, s3 = {};
    for (int c = 0; c < 16; c++) {
      const float* p = kvpart + pb + (size_t)c * 4096 + d * 64 + e0;
      s0 += *(const f32x4*)(p);
      s1 += *(const f32x4*)(p + 4);
      s2 += *(const f32x4*)(p + 8);
      s3 += *(const f32x4*)(p + 12);
    }
    s16x8 o0, o1;
#pragma unroll
    for (int j = 0; j < 4; j++) {
      o0[j] = (short)f2bf(s0[j]); o0[4 + j] = (short)f2bf(s1[j]);
      o1[j] = (short)f2bf(s2[j]); o1[4 + j] = (short)f2bf(s3[j]);
    }
    int ch0 = e0 >> 3;
    *(s16x8*)&kvls[d * 64 + (ch0 ^ (d & 7)) * 8] = o0;
    *(s16x8*)&kvls[d * 64 + ((ch0 + 1) ^ (d & 7)) * 8] = o1;
    __syncthreads();
    // C[d][n] = KV[d][e] @ woutt[n][h*64+e]^T ; wave w: n in [w*128, +128)
    f32x4 acc[4][8] = {};
#pragma unroll
    for (int kk = 0; kk < 2; kk++) {
      s16x8 af[4], bfr[8];
#pragma unroll
      for (int mf = 0; mf < 4; mf++) {
        int r = mf * 16 + lnlo;
        af[mf] = *(const s16x8*)&kvls[r * 64 + ((kk * 4 + lnhi) ^ (r & 7)) * 8];
      }
#pragma unroll
      for (int nf = 0; nf < 8; nf++) {
        int n = w * 128 + nf * 16 + lnlo;
        bfr[nf] = *(const s16x8*)&woutt[(size_t)n * 512 + h * 64 + (kk * 4 + lnhi) * 8];
      }
#pragma unroll
      for (int mf = 0; mf < 4; mf++)
#pragma unroll
        for (int nf = 0; nf < 8; nf++)
          acc[mf][nf] = __builtin_amdgcn_mfma_f32_16x16x32_bf16(af[mf], bfr[nf], acc[mf][nf], 0, 0, 0);
    }
#pragma unroll
    for (int mf = 0; mf < 4; mf++)
#pragma unroll
      for (int nf = 0; nf < 8; nf++) {
        int n = w * 128 + nf * 16 + lnlo;
        s16x4 o4;
#pragma unroll
        for (int r = 0; r < 4; r++) o4[r] = (short)f2bf(acc[mf][nf][r]);
        *(s16x4*)&w2t[(size_t)b * 262144 + (size_t)n * 512 + h * 64 + mf * 16 + lnhi * 4] = o4;
      }
  } else {
    int blk2 = blk - 64;
    int bh = blk2 >> 3, tch = blk2 & 7;
    if (tid < 64) {
      float s = 0.f;
#pragma unroll
      for (int c = 0; c < 16; c++) s += kspart[(size_t)bh * 1024 + c * 64 + tid];
      ksumv[tid] = s;
    }
    __syncthreads();
#pragma unroll
    for (int tt = 0; tt < 2; tt++) {
      int tok = tch * 512 + tid * 2 + tt;
      const u16* qp = qphi + ((size_t)bh * 4096 + tok) * 64;
      float den = 0.f;
#pragma unroll
      for (int cch = 0; cch < 8; cch++) {
        s16x8 v8 = *(const s16x8*)(qp + cch * 8);
        f32x4 k0 = *(const f32x4*)&ksumv[cch * 8];
        f32x4 k1 = *(const f32x4*)&ksumv[cch * 8 + 4];
#pragma unroll
        for (int j = 0; j < 4; j++) den += bf2f((u16)v8[j]) * k0[j];
#pragma unroll
        for (int j = 0; j < 4; j++) den += bf2f((u16)v8[4 + j]) * k1[j];
      }
      rdng[(size_t)bh * 4096 + tok] = 1.f / (den + 1e-6f);
    }
  }
}

// ----------------------------------------------------------------- k_out
// out[m][n] = (qphi_gather[m][k] * rdn) @ W2T[b][n][k] + bias[n].
// r4 K-loop; A reg-staged (gather across h-blocks, scaled by rdn during
// cvt->ds_write at end of phase b; loads issued phase a -> ~1-tile cover);
// B via gload_lds (3-buf). Compiler-inserted vmcnt at writeA drains older
// B-gloads (B(t+1) issued t-1 phase b is older than A(t+2) issued t phase a).
__global__ __launch_bounds__(512, 1) void k_out(
    const u16* __restrict__ qphi, const u16* __restrict__ w2t,
    const float* __restrict__ rdng, const float* __restrict__ bias,
    float* __restrict__ out) {
  __shared__ __align__(16) u16 lsA[3][256 * 32];
  __shared__ __align__(16) u16 lsB[3][256 * 32];
  int nwg = gridDim.x, bx = blockIdx.x;
  int o = (bx & 7) * (nwg >> 3) + (bx >> 3);
  int bm = o >> 1, bn = o & 1;
  int m0 = bm << 8, n0 = bn << 8;
  int b = m0 >> 12;
  int tid = threadIdx.x, w = tid >> 6, lane = tid & 63;
  int lnlo = lane & 15, lnhi = lane >> 4;
  int wr = w >> 2, wc = w & 3;

  int ldst[2];
  const u16* qb_[2]; const u16* gB_[2]; const float* rb_[2];
#pragma unroll
  for (int i = 0; i < 2; i++) {
    int c = tid + i * 512, row = c >> 2, ch = c & 3;
    int gch = ch ^ ((row >> 1) & 3);
    int tok = (m0 + row) & 4095;
    qb_[i] = qphi + ((size_t)(b * 8) * 4096 + tok) * 64 + gch * 8;
    rb_[i] = rdng + (size_t)(b * 8) * 4096 + tok;
    gB_[i] = w2t + (size_t)b * 262144 + (size_t)(n0 + row) * 512 + gch * 8;
    ldst[i] = c * 8;
  }
  int offA[8], offB[4];
#pragma unroll
  for (int f = 0; f < 8; f++) {
    int r = wr * 128 + f * 16 + lnlo;
    offA[f] = r * 32 + (lnhi ^ ((r >> 1) & 3)) * 8;
  }
#pragma unroll
  for (int f = 0; f < 4; f++) {
    int r = wc * 64 + f * 16 + lnlo;
    offB[f] = r * 32 + (lnhi ^ ((r >> 1) & 3)) * 8;
  }

  f32x4 acc[8][4] = {};
  s16x8 ar[2]; float rr[2];

  auto loadA = [&](int t) {
#pragma unroll
    for (int i = 0; i < 2; i++) {
      ar[i] = *(const s16x8*)(qb_[i] + (size_t)(t >> 1) * 262144 + (t & 1) * 32);
      rr[i] = rb_[i][(size_t)(t >> 1) * 4096];
    }
  };
  auto writeA = [&](int buf) {
#pragma unroll
    for (int i = 0; i < 2; i++) {
      s16x8 oo;
#pragma unroll
      for (int j = 0; j < 8; j++) oo[j] = (short)f2bf(bf2f((u16)ar[i][j]) * rr[i]);
      *(s16x8*)&lsA[buf][ldst[i]] = oo;
    }
  };
  auto stageB = [&](int t) {
    int buf = t % 3;
#pragma unroll
    for (int i = 0; i < 2; i++) gload16(gB_[i] + t * 32, &lsB[buf][ldst[i]]);
  };

  // prologue: A(0),A(1) synchronous reg->LDS; B(0),B(1) in flight
  loadA(0); writeA(0);
  loadA(1); writeA(1);
  stageB(0); stageB(1);
  asm volatile("s_waitcnt lgkmcnt(0)" ::: "memory");
  asm volatile("s_waitcnt vmcnt(2)" ::: "memory");   // B(0) landed; B(1) flying
  __builtin_amdgcn_s_barrier();

#pragma unroll
  for (int t = 0; t < 16; t++) {
    int buf = t % 3;
    const u16* La = &lsA[buf][0];
    const u16* Lb = &lsB[buf][0];

    s16x8 bf[4], af[4];
#pragma unroll
    for (int f = 0; f < 4; f++) bf[f] = *(const s16x8*)(Lb + offB[f]);
#pragma unroll
    for (int f = 0; f < 4; f++) af[f] = *(const s16x8*)(La + offA[f]);
    if (t < 14) loadA(t + 2);
    __builtin_amdgcn_s_barrier();
    __builtin_amdgcn_s_setprio(1);
#pragma unroll
    for (int mf = 0; mf < 4; mf++)
#pragma unroll
      for (int nf = 0; nf < 4; nf++)
        acc[mf][nf] = __builtin_amdgcn_mfma_f32_16x16x32_bf16(af[mf], bf[nf], acc[mf][nf], 0, 0, 0);
    __builtin_amdgcn_s_setprio(0);
    __builtin_amdgcn_s_barrier();

    s16x8 af2[4];
#pragma unroll
    for (int f = 0; f < 4; f++) af2[f] = *(const s16x8*)(La + offA[4 + f]);
    if (t < 14) stageB(t + 2);
    __builtin_amdgcn_s_barrier();
    __builtin_amdgcn_s_setprio(1);
#pragma unroll
    for (int mf = 0; mf < 4; mf++)
#pragma unroll
      for (int nf = 0; nf < 4; nf++)
        acc[4 + mf][nf] = __builtin_amdgcn_mfma_f32_16x16x32_bf16(af2[mf], bf[nf], acc[4 + mf][nf], 0, 0, 0);
    __builtin_amdgcn_s_setprio(0);
    if (t < 14) writeA((t + 2) % 3);     // compiler vmcnt drains B(t+1) too
    if (t == 14) asm volatile("s_waitcnt vmcnt(0)" ::: "memory");  // B(15)
    if (t < 15) {
      asm volatile("s_waitcnt lgkmcnt(0)" ::: "memory");
      __builtin_amdgcn_s_barrier();
    }
  }

  int gmB = m0 + wr * 128;
  int gnB = n0 + wc * 64;
#pragma unroll
  for (int mf = 0; mf < 8; mf++) {
#pragma unroll
    for (int nf = 0; nf < 4; nf++) {
      int col = gnB + nf * 16 + lnlo;
      float bv = bias[col];
#pragma unroll
      for (int r = 0; r < 4; r++) {
        int rowm = gmB + mf * 16 + lnhi * 4 + r;
        out[(size_t)rowm * 512 + col] = acc[mf][nf][r] + bv;
      }
    }
  }
}

// ------------------------------------------------------------------ launch
#define OFF_XB     ((size_t)0)             // 33.5MB xb; after GEMM1: w2t+rdn
#define OFF_W2T    ((size_t)0)             //  4,194,304 (alias xb)
#define OFF_RDN    ((size_t)4194304)       //  1,048,576 (alias xb)
#define OFF_WQKVT  ((size_t)33554432)      //  1,572,864
#define OFF_WOUTT  ((size_t)35127296)      //    524,288
#define OFF_QPHI   ((size_t)35651584)      // 33,554,432
#define OFF_KPHI   ((size_t)69206016)      // 33,554,432 (kphiT [bh][64][4096])
#define OFF_VBUF   ((size_t)102760448)     // 33,554,432 (vT    [bh][64][4096])
#define OFF_KVPART ((size_t)136314880)     // 16,777,216
#define OFF_KSPART ((size_t)153092096)     //    262,144

extern "C" void kernel_launch(void* const* d_in, const int* in_sizes, int n_in,
                              void* d_out, int out_size, void* d_ws, size_t ws_size,
                              hipStream_t stream) {
  const float* x    = (const float*)d_in[0];
  const float* Wqkv = (const float*)d_in[1];
  const float* Wout = (const float*)d_in[2];
  const float* bout = (const float*)d_in[3];
  float* out = (float*)d_out;
  char* ws = (char*)d_ws;

  u16* xb     = (u16*)(ws + OFF_XB);
  u16* w2t    = (u16*)(ws + OFF_W2T);   // alias: xb dead after GEMM1
  float* rdng = (float*)(ws + OFF_RDN); // alias: xb dead after GEMM1
  u16* wqkvt  = (u16*)(ws + OFF_WQKVT);
  u16* woutt  = (u16*)(ws + OFF_WOUTT);
  u16* qphi   = (u16*)(ws + OFF_QPHI);
  u16* kphT   = (u16*)(ws + OFF_KPHI);
  u16* vT     = (u16*)(ws + OFF_VBUF);
  float* kvpart = (float*)(ws + OFF_KVPART);
  float* kspart = (float*)(ws + OFF_KSPART);

  k_prep<<<2304, 256, 0, stream>>>(x, xb, Wqkv, wqkvt, Wout, woutt);
  k_gemm1<<<768, 512, 0, stream>>>(xb, wqkvt, qphi, kphT, vT);
  k_kv<<<1024, 256, 0, stream>>>(kphT, vT, kvpart, kspart);
  k_w2<<<576, 256, 0, stream>>>(kvpart, kspart, woutt, qphi, w2t, rdng);
  k_out<<<256, 512, 0, stream>>>(qphi, w2t, rdng, bout, out);
}